// Round 2
// baseline (303.090 us; speedup 1.0000x reference)
//
#include <hip/hip_runtime.h>

// PopulationODE: explicit Euler, L=512, B=32768, 4 states, 21 weights.
// Output [L,4,B] fp32 = 256 MiB, write-bound (harness fill rate: 6.6 TB/s).
//
// R0 (single pass, 2 waves/CU): ~110 µs kernel — store-ack (vmcnt) hazard on
//   state registers, no co-resident waves to hide it.
// R1 (checkpoint kernel + segment kernel): ~126 µs — serial K1 doesn't overlap
//   with K2, two launch tails.
// R2 (this): ONE dispatch, redundant recompute. Block = (segment, column):
//   recompute seg*32 steps from y0 in registers (no stores, bit-identical op
//   sequence), then 32 store-steps for rows seg*32 .. seg*32+31.
//   - 4 trajectories/thread -> float4 stores (1 KiB/wave-store, fill-like).
//   - Balanced mapping: blocks c and c+256 share a CU (round-robin) and get
//     segments s and 15-s -> every CU does 480+64 steps total.
//   - Redundant VALU (~33 µs aggregate) overlaps with HBM store drain (~40 µs).

#define ODE_L 512
#define ODE_B 32768
#define SEG   32
#define NSEG  (ODE_L / SEG)     // 16
#define TPB   256
#define PACK  4                 // trajectories per thread
#define BPB   (TPB * PACK)      // 1024 b-values per block
#define NCOL  (ODE_B / BPB)     // 32 column-blocks per segment

// One Euler step for one trajectory (identical arithmetic to R0 kernel).
#define ODE_STEP1(A, T, N, C, h)                                             \
  do {                                                                       \
    const float dA = w0  + w1  * A + w2  * A * A;                            \
    const float dT = w3  + w4  * T + w5  * T * T + w6  * A + w7  * A * A +   \
                     w8  * A * T;                                            \
    const float dN = w9  + w10 * N + w11 * N * N + w12 * T + w13 * T * T +   \
                     w14 * T * N;                                            \
    const float dC = w15 + w16 * C + w17 * C * C + w18 * N + w19 * N * N +   \
                     w20 * N * C;                                            \
    A += h * dA; T += h * dT; N += h * dN; C += h * dC;                      \
  } while (0)

#define ODE_STEP4(h)                                                         \
  do {                                                                       \
    ODE_STEP1(A0, T0, N0, C0, h);                                            \
    ODE_STEP1(A1, T1, N1, C1, h);                                            \
    ODE_STEP1(A2, T2, N2, C2, h);                                            \
    ODE_STEP1(A3, T3, N3, C3, h);                                            \
  } while (0)

__global__ __launch_bounds__(TPB, 2) void ode_fused_kernel(
    const float* __restrict__ s_grid,   // [L]
    const float* __restrict__ y0,       // [4, B]
    const float* __restrict__ w,        // [21]
    float* __restrict__ out)            // [L, 4, B]
{
    __shared__ float sh_h[ODE_L - 1];   // h[i] = s[i+1]-s[i], i in [0,511)

    const int tid = threadIdx.x;
    for (int i = tid; i < ODE_L - 1; i += TPB) {
        sh_h[i] = s_grid[i + 1] - s_grid[i];
    }

    // Uniform weights -> scalar loads/SGPRs.
    const float w0  = w[0],  w1  = w[1],  w2  = w[2];
    const float w3  = w[3],  w4  = w[4],  w5  = w[5],  w6  = w[6],  w7 = w[7],
                w8  = w[8];
    const float w9  = w[9],  w10 = w[10], w11 = w[11], w12 = w[12],
                w13 = w[13], w14 = w[14];
    const float w15 = w[15], w16 = w[16], w17 = w[17], w18 = w[18],
                w19 = w[19], w20 = w[20];

    __syncthreads();

    // Balanced block -> (segment, column) mapping.
    // half 0: idx 0..255 -> seg = idx&15,      col = idx>>4        (cols 0..15)
    // half 1: idx 0..255 -> seg = 15-(idx&15), col = 16 + (idx>>4) (cols 16..31)
    // Blocks c and c+256 land on the same CU (round-robin) with segments
    // s and 15-s -> per-CU work is constant (480 recompute + 64 store steps).
    const int bid  = blockIdx.x;
    const int half = bid >> 8;
    const int idx  = bid & 255;
    const int seg  = half ? (15 - (idx & 15)) : (idx & 15);
    const int col  = (idx >> 4) + (half << 4);
    const int b0   = col * BPB + tid * PACK;

    // Load 4 trajectories' initial state (float4, coalesced).
    float4 vA = *reinterpret_cast<const float4*>(&y0[0 * ODE_B + b0]);
    float4 vT = *reinterpret_cast<const float4*>(&y0[1 * ODE_B + b0]);
    float4 vN = *reinterpret_cast<const float4*>(&y0[2 * ODE_B + b0]);
    float4 vC = *reinterpret_cast<const float4*>(&y0[3 * ODE_B + b0]);

    float A0 = vA.x, A1 = vA.y, A2 = vA.z, A3 = vA.w;
    float T0 = vT.x, T1 = vT.y, T2 = vT.z, T3 = vT.w;
    float N0 = vN.x, N1 = vN.y, N2 = vN.z, N3 = vN.w;
    float C0 = vC.x, C1 = vC.y, C2 = vC.z, C3 = vC.w;

    // ---- Recompute phase: apply h[0 .. seg*32-1], registers only. ----
    for (int c = 0; c < seg; ++c) {
        const int base_h = c * SEG;
        #pragma unroll 8
        for (int j = 0; j < SEG; ++j) {
            const float h = sh_h[base_h + j];
            ODE_STEP4(h);
        }
    }

    // ---- Store phase: rows i0 .. i0+31. Row i0 is the current state. ----
    const int i0 = seg * SEG;
    {
        const size_t base = (size_t)i0 * (4 * ODE_B) + (size_t)b0;
        *reinterpret_cast<float4*>(&out[base + 0 * ODE_B]) = make_float4(A0, A1, A2, A3);
        *reinterpret_cast<float4*>(&out[base + 1 * ODE_B]) = make_float4(T0, T1, T2, T3);
        *reinterpret_cast<float4*>(&out[base + 2 * ODE_B]) = make_float4(N0, N1, N2, N3);
        *reinterpret_cast<float4*>(&out[base + 3 * ODE_B]) = make_float4(C0, C1, C2, C3);
    }
    #pragma unroll 8
    for (int j = 1; j < SEG; ++j) {
        const float h = sh_h[i0 + j - 1];
        ODE_STEP4(h);
        const size_t base = (size_t)(i0 + j) * (4 * ODE_B) + (size_t)b0;
        *reinterpret_cast<float4*>(&out[base + 0 * ODE_B]) = make_float4(A0, A1, A2, A3);
        *reinterpret_cast<float4*>(&out[base + 1 * ODE_B]) = make_float4(T0, T1, T2, T3);
        *reinterpret_cast<float4*>(&out[base + 2 * ODE_B]) = make_float4(N0, N1, N2, N3);
        *reinterpret_cast<float4*>(&out[base + 3 * ODE_B]) = make_float4(C0, C1, C2, C3);
    }
}

extern "C" void kernel_launch(void* const* d_in, const int* in_sizes, int n_in,
                              void* d_out, int out_size, void* d_ws, size_t ws_size,
                              hipStream_t stream) {
    (void)in_sizes; (void)n_in; (void)d_ws; (void)ws_size; (void)out_size;

    const float* s_grid = (const float*)d_in[0];
    const float* y0     = (const float*)d_in[1];
    const float* w      = (const float*)d_in[2];
    float* out          = (float*)d_out;

    // 16 segments x 32 column-blocks = 512 blocks x 256 threads (4 traj/thread).
    ode_fused_kernel<<<dim3(NSEG * NCOL), dim3(TPB), 0, stream>>>(
        s_grid, y0, w, out);
}

// Round 3
// 265.017 us; speedup vs baseline: 1.1437x; 1.1437x over previous
//
#include <hip/hip_runtime.h>

// PopulationODE: explicit Euler, L=512, B=32768, 4 states, 21 weights.
// Output [L,4,B] fp32 = 256 MiB -> write-bound (harness fill: 6.6 TB/s).
//
// History: R0 single-pass 1-traj/thread ~110us kernel (store-ack stall per
// step); R1 checkpoint split ~126us (serialized phases); R2 redundant
// recompute ~141us (8.5x VALU redundancy + undefined block->CU balance).
// R3: back to single-pass, ZERO redundant compute, but break the per-step
// store->register-reuse hazard with a double-buffered register staging pipe:
//   - compute 8 steps into staging regs (half 0), issue 32 stores,
//     compute next 8 into half 1, issue, repeat.
//   - a staging reg is reused ~16 steps / 64 stores after its store was
//     issued -> compiler emits large-N vmcnt, store latency fully pipelined
//     (T4 counted-vmcnt effect via reuse distance alone).
//   - unsigned element offsets -> saddr + 32-bit voffset stores, 1 addr
//     add per row; all staging indices compile-time (no scratch).
// Floor: 256 MiB / 6.6 TB/s = 41 us writes; ~16-20 us VALU issue (overlapped).

#define ODE_L 512
#define ODE_B 32768
#define G     8   // steps per staging group (32 stores in flight per group)

// One Euler step (identical arithmetic to the verified R0 kernel).
#define ODE_STEP(h)                                                          \
  do {                                                                       \
    const float dA = w0  + w1  * A + w2  * A * A;                            \
    const float dT = w3  + w4  * T + w5  * T * T + w6  * A + w7  * A * A +   \
                     w8  * A * T;                                            \
    const float dN = w9  + w10 * N + w11 * N * N + w12 * T + w13 * T * T +   \
                     w14 * T * N;                                            \
    const float dC = w15 + w16 * C + w17 * C * C + w18 * N + w19 * N * N +   \
                     w20 * N * C;                                            \
    A += h * dA; T += h * dT; N += h * dN; C += h * dC;                      \
  } while (0)

// Compute G steps starting at row R0V into staging half OFS (compile-time),
// then issue the 4*G stores. R0V may be runtime; OFS+j is always constant.
#define ODE_GROUP(OFS, R0V)                                                  \
  do {                                                                       \
    _Pragma("unroll")                                                        \
    for (int j = 0; j < G; ++j) {                                            \
      const float h = sh_h[(R0V) + j - 1];                                   \
      ODE_STEP(h);                                                           \
      bA[(OFS) + j] = A; bT[(OFS) + j] = T;                                  \
      bN[(OFS) + j] = N; bC[(OFS) + j] = C;                                  \
    }                                                                        \
    _Pragma("unroll")                                                        \
    for (int j = 0; j < G; ++j) {                                            \
      const unsigned o = ((R0V) + j) * (4u * ODE_B) + b;                     \
      out[o + 0u * ODE_B] = bA[(OFS) + j];                                   \
      out[o + 1u * ODE_B] = bT[(OFS) + j];                                   \
      out[o + 2u * ODE_B] = bN[(OFS) + j];                                   \
      out[o + 3u * ODE_B] = bC[(OFS) + j];                                   \
    }                                                                        \
  } while (0)

__global__ __launch_bounds__(64) void population_ode_kernel(
    const float* __restrict__ s_grid,   // [L]
    const float* __restrict__ y0,       // [4, B]
    const float* __restrict__ w,        // [21]
    float* __restrict__ out)            // [L, 4, B]
{
    __shared__ float sh_h[ODE_L - 1];   // h[i] = s[i+1] - s[i]

    const int tid = threadIdx.x;
    #pragma unroll
    for (int i = tid; i < ODE_L - 1; i += 64) {
        sh_h[i] = s_grid[i + 1] - s_grid[i];
    }

    // Uniform weights -> scalar loads / SGPRs.
    const float w0  = w[0],  w1  = w[1],  w2  = w[2];
    const float w3  = w[3],  w4  = w[4],  w5  = w[5],  w6  = w[6],  w7 = w[7],
                w8  = w[8];
    const float w9  = w[9],  w10 = w[10], w11 = w[11], w12 = w[12],
                w13 = w[13], w14 = w[14];
    const float w15 = w[15], w16 = w[16], w17 = w[17], w18 = w[18],
                w19 = w[19], w20 = w[20];

    __syncthreads();

    const unsigned b = blockIdx.x * 64u + (unsigned)tid;

    float A = y0[0 * ODE_B + b];
    float T = y0[1 * ODE_B + b];
    float N = y0[2 * ODE_B + b];
    float C = y0[3 * ODE_B + b];

    // Row 0 is y0 itself.
    out[0u * ODE_B + b] = A;
    out[1u * ODE_B + b] = T;
    out[2u * ODE_B + b] = N;
    out[3u * ODE_B + b] = C;

    // Double-buffered staging registers: two halves of G rows each.
    float bA[2 * G], bT[2 * G], bN[2 * G], bC[2 * G];

    // Rows 1..496: 31 iterations x 2 groups of 8 (statically indexed halves).
    for (unsigned g = 0; g < 31; ++g) {
        const unsigned r0 = 1u + g * (2 * G);
        ODE_GROUP(0, r0);
        ODE_GROUP(G, r0 + G);
    }

    // Rows 497..504: one more full group (half 0).
    ODE_GROUP(0, 497u);

    // Tail rows 505..511 (7 steps) into half 1.
    #pragma unroll
    for (int j = 0; j < 7; ++j) {
        const float h = sh_h[504 + j];
        ODE_STEP(h);
        bA[G + j] = A; bT[G + j] = T; bN[G + j] = N; bC[G + j] = C;
    }
    #pragma unroll
    for (int j = 0; j < 7; ++j) {
        const unsigned o = (505u + j) * (4u * ODE_B) + b;
        out[o + 0u * ODE_B] = bA[G + j];
        out[o + 1u * ODE_B] = bT[G + j];
        out[o + 2u * ODE_B] = bN[G + j];
        out[o + 3u * ODE_B] = bC[G + j];
    }
}

extern "C" void kernel_launch(void* const* d_in, const int* in_sizes, int n_in,
                              void* d_out, int out_size, void* d_ws, size_t ws_size,
                              hipStream_t stream) {
    (void)in_sizes; (void)n_in; (void)d_ws; (void)ws_size; (void)out_size;

    const float* s_grid = (const float*)d_in[0];
    const float* y0     = (const float*)d_in[1];
    const float* w      = (const float*)d_in[2];
    float* out          = (float*)d_out;

    // One thread per trajectory: 512 blocks x 64 threads = 512 waves (2/CU).
    population_ode_kernel<<<dim3(ODE_B / 64), dim3(64), 0, stream>>>(
        s_grid, y0, w, out);
}